// Round 14
// baseline (415.009 us; speedup 1.0000x reference)
//
#include <hip/hip_runtime.h>

#define WL 512   // window_len (t and o dims)
#define NV 64    // n_var
#define LR 16    // low rank
#define NB 512   // batch

__device__ __forceinline__ float tanh_fast(float x) {
    // tanh(x) = 1 - 2/(exp(2x)+1); exact at +-inf saturation, ~1e-7 abs err
    float e = __expf(2.0f * x);
    return 1.0f - 2.0f / (e + 1.0f);
}

// K1: tmp[b,k,v] = sum_t tanh(g[v]*x[b,t,v]) * A[t,k]
// grid = 512 (one block per b), block = 1024 threads (16 waves).
// (byte-identical to R7's verified version; ~16us standalone)
__global__ __launch_bounds__(1024, 8) void k_tmp(
    const float* __restrict__ x, const float* __restrict__ gating,
    const float* __restrict__ A, float* __restrict__ tmp)
{
    __shared__ float red[16 * LR * NV];  // 64 KiB (16 partials x 1024 (k,v))
    const int tid = threadIdx.x;
    const int b = blockIdx.x;

    const int v = tid & 63;
    const int tg = __builtin_amdgcn_readfirstlane(tid >> 6);
    const float g = gating[v];

    float acc[LR];
#pragma unroll
    for (int k = 0; k < LR; ++k) acc[k] = 0.f;

    const float* xb = x + (size_t)b * (WL * NV) + (size_t)tg * 32 * NV + v;
    const float* Abase = A + (size_t)tg * 32 * LR;

#pragma unroll 4
    for (int i = 0; i < 32; ++i) {
        const float x1 = tanh_fast(g * xb[i * NV]);      // 256B/wave, coalesced
        const float* Ar = Abase + i * LR;                // wave-uniform -> s_load
#pragma unroll
        for (int k = 0; k < LR; ++k) acc[k] = fmaf(x1, Ar[k], acc[k]);
    }

#pragma unroll
    for (int k = 0; k < LR; ++k) red[(tg * LR + k) * NV + v] = acc[k];
    __syncthreads();

    {
        const int p = tid;
        float s = 0.f;
#pragma unroll
        for (int t = 0; t < 16; ++t) s += red[t * (LR * NV) + p];
        tmp[(size_t)b * (LR * NV) + p] = s;
    }
}

// K2: out[b,o,v] = x[b,o,v] + bias[o,v] + sum_k tmp[b,k,v]*B[k,o,v]
// grid = (64 b-chunks of 8) x (32 o-tiles of 16), block = 256 (4 waves)
// thread: v = tid&63, wave og = tid>>6 owns o = oTile*16 + og*4 + j, j=0..3
//
// == R2's 31.3us structure + ONE change: memcpy-style x-load batch. ==
// Evidence: every K2 variant consumed its x load (43MB HBM-miss, ~500-900cy)
// within ~100cy of issue; 1-deep "prefetches" were sunk back to the use site
// by the scheduler (R4/R5/R12 nulls). The 6.9 TB/s fill kernel wins at 8%
// occupancy by having no load->use chain. Here: issue ALL 32 x loads (8 b x
// 4 o) at block start, asm-pin them (forces the scheduler to keep them in
// flight and take ONE vmcnt drain instead of 8 exposed stalls), then the
// batch loop runs load-free on x. B-refetch/tmp/stores/FMA order unchanged.
// waves_per_eu(4,4): 128-VGPR budget (need ~90), 16 waves/CU cap ~= R2's
// measured 12 — occupancy unharmed, allocator cannot halve the budget.
__global__ __attribute__((amdgpu_flat_work_group_size(256, 256),
                          amdgpu_waves_per_eu(4, 4)))
void k_out(
    const float* __restrict__ x, const float* __restrict__ bias,
    const float* __restrict__ Bm, const float* __restrict__ tmp,
    float* __restrict__ out)
{
    const int tid = threadIdx.x;
    const int v = tid & 63;
    const int og = tid >> 6;
    const int o_base = blockIdx.y * 16 + og * 4;
    const int b0 = blockIdx.x * 8;

    // issue all 32 x loads up front (independent, 256B/wave each, coalesced)
    float xall[8][4];
#pragma unroll
    for (int bi = 0; bi < 8; ++bi) {
        const float* xb = x + (size_t)(b0 + bi) * WL * NV;
#pragma unroll
        for (int j = 0; j < 4; ++j)
            xall[bi][j] = xb[(o_base + j) * NV + v];
    }
    // pin: compiler must materialize all 32 here (one waitcnt), cannot sink
    // the loads into the batch loop
#pragma unroll
    for (int bi = 0; bi < 8; ++bi)
#pragma unroll
        for (int j = 0; j < 4; ++j)
            asm volatile("" : "+v"(xall[bi][j]));

    float breg[4];
#pragma unroll
    for (int j = 0; j < 4; ++j) breg[j] = bias[(o_base + j) * NV + v];

#pragma unroll
    for (int bi = 0; bi < 8; ++bi) {
        const int b = b0 + bi;
        const float* tb = tmp + (size_t)b * (LR * NV) + v;
        float tr[LR];
#pragma unroll
        for (int k = 0; k < LR; ++k) tr[k] = tb[k * NV];     // L1/L2-resident
        float* ob = out + (size_t)b * WL * NV;
#pragma unroll
        for (int j = 0; j < 4; ++j) {
            const int o = o_base + j;
            float acc = breg[j];
#pragma unroll
            for (int k = 0; k < LR; ++k)
                acc += tr[k] * Bm[((size_t)k * WL + o) * NV + v];  // L1-hot refetch
            ob[o * NV + v] = xall[bi][j] + acc;
        }
    }
}

extern "C" void kernel_launch(void* const* d_in, const int* in_sizes, int n_in,
                              void* d_out, int out_size, void* d_ws, size_t ws_size,
                              hipStream_t stream) {
    const float* x      = (const float*)d_in[0];  // [512,512,64,1]
    const float* gating = (const float*)d_in[1];  // [64]
    const float* bias   = (const float*)d_in[2];  // [512,64]
    const float* A      = (const float*)d_in[3];  // [512,16]
    const float* Bm     = (const float*)d_in[4];  // [16,512,64]
    float* out = (float*)d_out;
    float* tmp = (float*)d_ws;                    // 2 MiB scratch ([b,k,v])

    k_tmp<<<NB, 1024, 0, stream>>>(x, gating, A, tmp);
    k_out<<<dim3(64, 32), 256, 0, stream>>>(x, bias, Bm, tmp, out);
}

// Round 15
// 49.401 us; speedup vs baseline: 8.4008x; 8.4008x over previous
//
#include <hip/hip_runtime.h>

#define WL 512   // window_len (t and o dims)
#define NV 64    // n_var
#define LR 16    // low rank
#define NB 512   // batch
#define BB 16    // batches per k_out block
#define OO 16    // o-rows per k_out block

__device__ __forceinline__ float tanh_fast(float x) {
    // tanh(x) = 1 - 2/(exp(2x)+1); exact at +-inf saturation, ~1e-7 abs err
    float e = __expf(2.0f * x);
    return 1.0f - 2.0f / (e + 1.0f);
}

// K1: tmp[b,k,v] = sum_t tanh(g[v]*x[b,t,v]) * A[t,k]
// grid = 512 (one block per b), block = 1024 threads (16 waves).
// (byte-identical to R7's verified version; ~16us standalone)
__global__ __launch_bounds__(1024, 8) void k_tmp(
    const float* __restrict__ x, const float* __restrict__ gating,
    const float* __restrict__ A, float* __restrict__ tmp)
{
    __shared__ float red[16 * LR * NV];  // 64 KiB (16 partials x 1024 (k,v))
    const int tid = threadIdx.x;
    const int b = blockIdx.x;

    const int v = tid & 63;
    const int tg = __builtin_amdgcn_readfirstlane(tid >> 6);
    const float g = gating[v];

    float acc[LR];
#pragma unroll
    for (int k = 0; k < LR; ++k) acc[k] = 0.f;

    const float* xb = x + (size_t)b * (WL * NV) + (size_t)tg * 32 * NV + v;
    const float* Abase = A + (size_t)tg * 32 * LR;

#pragma unroll 4
    for (int i = 0; i < 32; ++i) {
        const float x1 = tanh_fast(g * xb[i * NV]);      // 256B/wave, coalesced
        const float* Ar = Abase + i * LR;                // wave-uniform -> s_load
#pragma unroll
        for (int k = 0; k < LR; ++k) acc[k] = fmaf(x1, Ar[k], acc[k]);
    }

#pragma unroll
    for (int k = 0; k < LR; ++k) red[(tg * LR + k) * NV + v] = acc[k];
    __syncthreads();

    {
        const int p = tid;
        float s = 0.f;
#pragma unroll
        for (int t = 0; t < 16; ++t) s += red[t * (LR * NV) + p];
        tmp[(size_t)b * (LR * NV) + p] = s;
    }
}

// K2: out[b,o,v] = x[b,o,v] + bias[o,v] + sum_k tmp[b,k,v]*B[k,o,v]
// grid = (32 b-chunks of 16) x (32 o-tiles of 16), block = 512 (8 waves)
// thread: v = tid&63, wave wv = tid>>6 owns o_local = wv*2 + {0,1}
//
// THE WALL (finally measured): R2-K2 pushed 2048 blocks x 512 KB = 1.07 GB
// of B-panel bytes through L1 (8x refetch per block) = 1.07GB/(256CU x
// 64B/cy x 2.4GHz) ~= 27us -> K2 was L1-BW-bound on B. (R14's accident
// proved it: when unrolling broke B's L1 locality, FETCH hit 470MB and K2
// went 13x slower.) Fix = stage B in LDS ONCE per block, 16-batch reuse:
// L1-B bytes drop 16x (1.07GB -> 67MB); LDS serves reuse at 128B/cy.
// R11 failure mode (8 waves/CU) avoided: 512-thr blocks, B_lds-only 64KB
// -> LDS pins 2 blocks/CU = 16 waves/CU.
// R12 failure mode (allocator half-grant 52 < demand) avoided: demand ~62
// (Breg[2][16] read from LDS once + tr[16], NO prefetch buffers) and
// launch_bounds(512,2) -> cap 256, half-grant ~128 >= demand. Occupancy is
// governed by LDS, not launch_bounds — budget and occupancy decoupled.
// FMA order per output identical to R2 -> absmax unchanged.
__global__ __launch_bounds__(512, 2) void k_out(
    const float* __restrict__ x, const float* __restrict__ bias,
    const float* __restrict__ Bm, const float* __restrict__ tmp,
    float* __restrict__ out)
{
    __shared__ float B_lds[OO * LR * NV];  // [o_local][k][v] = 64 KiB
    const int tid = threadIdx.x;
    const int v = tid & 63;
    const int wv = tid >> 6;               // 0..7
    const int o0 = blockIdx.y * OO;
    const int b0 = blockIdx.x * BB;

    // stage B slice: 16 o x 16 k x 64 v = 16384 floats = 4096 float4, 8/thread
#pragma unroll
    for (int it = 0; it < 8; ++it) {
        const int fidx = it * 512 + tid;   // 0..4095
        const int ko = fidx >> 4;          // 0..255
        const int v4 = fidx & 15;
        const int ol = ko >> 4;            // 0..15
        const int k  = ko & 15;
        const float4 val = *(const float4*)(Bm + ((size_t)k * WL + (o0 + ol)) * NV + v4 * 4);
        *(float4*)(B_lds + ((ol * LR + k) * NV) + v4 * 4) = val;
    }
    __syncthreads();

    // each thread's 2 o-rows: pull B into registers ONCE (32 conflict-free ds_read)
    const int ol0 = wv * 2;
    float Breg[2][LR];
#pragma unroll
    for (int j = 0; j < 2; ++j)
#pragma unroll
        for (int k = 0; k < LR; ++k)
            Breg[j][k] = B_lds[((ol0 + j) * LR + k) * NV + v];
    float breg[2];
#pragma unroll
    for (int j = 0; j < 2; ++j) breg[j] = bias[(o0 + ol0 + j) * NV + v];

#pragma unroll 1
    for (int bl = 0; bl < BB; ++bl) {
        const int b = b0 + bl;
        const float* tb = tmp + (size_t)b * (LR * NV) + v;
        float tr[LR];
#pragma unroll
        for (int k = 0; k < LR; ++k) tr[k] = tb[k * NV];     // 4KB slice, L1-hot
        const float* xb = x + (size_t)b * (WL * NV);
        float* ob = out + (size_t)b * (WL * NV);
#pragma unroll
        for (int j = 0; j < 2; ++j) {
            const int o = o0 + ol0 + j;
            float acc = breg[j];
#pragma unroll
            for (int k = 0; k < LR; ++k) acc += tr[k] * Breg[j][k];
            ob[o * NV + v] = xb[o * NV + v] + acc;           // coalesced 256B/wave
        }
    }
}

extern "C" void kernel_launch(void* const* d_in, const int* in_sizes, int n_in,
                              void* d_out, int out_size, void* d_ws, size_t ws_size,
                              hipStream_t stream) {
    const float* x      = (const float*)d_in[0];  // [512,512,64,1]
    const float* gating = (const float*)d_in[1];  // [64]
    const float* bias   = (const float*)d_in[2];  // [512,64]
    const float* A      = (const float*)d_in[3];  // [512,16]
    const float* Bm     = (const float*)d_in[4];  // [16,512,64]
    float* out = (float*)d_out;
    float* tmp = (float*)d_ws;                    // 2 MiB scratch ([b,k,v])

    k_tmp<<<NB, 1024, 0, stream>>>(x, gating, A, tmp);
    k_out<<<dim3(32, 32), 512, 0, stream>>>(x, bias, Bm, tmp, out);
}